// Round 22
// baseline (259.335 us; speedup 1.0000x reference)
//
#include <hip/hip_runtime.h>

#define HH 512
#define WW 512
#define HW (512*512)
#define NB 8
#define ND 16
#define TW 64            // tile width (output)
#define TH 32            // tile height (output)
#define VR 42            // v-sum rows = TH+10
#define PTW 172          // words/row: 84 cols x {F,P} + 4 pad; 172/4=43 odd ->
                         // row-lane b128 hits all 8 bank-quads bijectively

__device__ __forceinline__ int reflect(int v) {
    if (v < 0) v = -v;
    if (v >= HH) v = 2*HH - 2 - v;
    return v;
}

// ---------------- Prepass: {mean_I, 1/(var_I+eps)} interleaved float2 ----------------
__global__ __launch_bounds__(256) void img_stats(const float* __restrict__ img,
                                                 float2* __restrict__ miv) {
    const int VRs = 42, PTs = 86, THs = 32, TWs = 64;
    __shared__ __align__(16) float hBuf[2*VRs*PTs + 20];
    float* hF = hBuf;
    float* hP = hBuf + VRs*PTs + 20;

    int blk  = blockIdx.x;
    int tile = blk & 127;
    int b    = blk >> 7;
    int ty0  = (tile >> 3) * THs;
    int tx0  = (tile & 7)  * TWs;

    const float inv121 = 1.0f/121.0f;
    const float* ib = img + (size_t)b*HW;
    const int t = threadIdx.x;

    if (t < 252) {
        int seg = t / 84, col = t - seg*84;
        int gx = reflect(tx0 - 10 + col);
        const float* icol = ib + gx;
        int vr0 = seg*14;
        float rv[11], rq[11];
        float sv = 0.f, sq = 0.f;
        #pragma unroll
        for (int j = 0; j < 10; ++j) {
            int gy = reflect(ty0 - 10 + vr0 + j);
            float v = icol[gy*WW], q = v*v;
            rv[j] = v; rq[j] = q; sv += v; sq += q;
        }
        #pragma unroll
        for (int k = 0; k < 14; ++k) {
            int vr = vr0 + k;
            int gy = reflect(ty0 + vr);
            float v = icol[gy*WW], q = v*v;
            sv += v; sq += q;
            hF[vr*PTs + col] = sv;
            hP[vr*PTs + col] = sq;
            sv -= rv[k%11]; sq -= rq[k%11];
            rv[(k+10)%11] = v; rq[(k+10)%11] = q;
        }
    }
    __syncthreads();

    if (t < 168) {
        int arr = t & 1;
        int j2  = t >> 1;
        int seg = (j2 >= 42) ? 1 : 0;
        int vr  = j2 - seg*42;
        int xb = seg ? 38 : 0;
        int nout = seg ? 18 : 19;
        float* rA = (arr ? hP : hF) + vr*PTs;
        float2 ring[5];
        float T = 0.f;
        #pragma unroll
        for (int j = 0; j < 5; ++j) {
            float2 v = *(float2*)(rA + xb + 2*j);
            ring[j] = v; T += v.x + v.y;
        }
        #pragma unroll
        for (int k2 = 0; k2 < 19; ++k2) {
            if (k2 < nout) {
                int hc = xb + 2*k2;
                float2 p = *(float2*)(rA + hc + 10);
                float2 q = ring[k2 % 5];
                float O0 = T + p.x;
                float O1 = O0 + p.y - q.x;
                T = O1 - q.y;
                ring[k2 % 5] = p;
                float2 o; o.x = O0*inv121; o.y = O1*inv121;
                *(float2*)(rA + hc + 10*seg) = o;
            }
        }
    }
    __syncthreads();

    float2* mb = miv + (size_t)b*HW;
    for (int i = t; i < THs*TWs; i += 256) {
        int y = i >> 6, x = i & 63;
        int vr = y + 5, hc = x + 5;
        int slot = hc + ((hc >= 38) ? 10 : 0);
        float mI  = hF[vr*PTs + slot];
        float mII = hP[vr*PTs + slot];
        float var = mII - mI*mI;
        float2 o; o.x = mI; o.y = 1.0f / (var + 1e-8f);
        mb[(ty0 + y)*WW + tx0 + x] = o;
    }
}

// ---------------- Main fused kernel: one (b,d) channel, one 64x32 tile, 512 thr --------
// R19 structure at TH=32: LDS 42*172*4 = 28.9 KB -> 4 blocks/CU x 8 waves = 32
// waves/CU (hardware max). launch_bounds(512,8) matches. Prefetch-4 in B/C/D.
// Row maps use boundary 16: prow(y) = y + 10*(y>=16). Column maps unchanged.
// Prefetch safety (depth 4): C seg1 prefetch row 30+k read at iter k, overwritten
// at iter k+4; B/D margins as in R19 (column geometry identical).
__global__ __launch_bounds__(512, 8) void guided_main(const float* __restrict__ feat,
                                                      const float* __restrict__ img,
                                                      const float2* __restrict__ miv,
                                                      float* __restrict__ out) {
    __shared__ __align__(16) float S[VR*PTW];

    int blk  = blockIdx.x;
    int tile = blk & 127;        // 8 col-tiles x 16 row-tiles
    int bd   = blk >> 7;
    int b    = bd >> 4;
    int ty0  = (tile >> 3) * TH;
    int tx0  = (tile & 7)  * TW;

    const float inv121 = 1.0f/121.0f;
    const float* fb   = feat + (size_t)bd*HW;
    const float* ib   = img  + (size_t)b*HW;
    const float2* mivb = miv + (size_t)b*HW;
    const int t = threadIdx.x;

    // ---- Phase A: vertical raw 11-sums; one b64 {sf,sp} store (writes only) ----
    // 84 cols x 3 row-segs (14 outputs each, exact) = 252 threads.
    if (t < 252) {
        int seg = t / 84, col = t - seg*84;
        int gx = reflect(tx0 - 10 + col);
        const float* fcol = fb + gx;
        const float* icol = ib + gx;
        int vr0 = seg*14;
        float rf[11], rp[11];
        float sf = 0.f, sp = 0.f;
        #pragma unroll
        for (int j = 0; j < 10; ++j) {
            int gy = reflect(ty0 - 10 + vr0 + j);
            float f = fcol[gy*WW], im = icol[gy*WW];
            float p = f*im;
            rf[j] = f; rp[j] = p; sf += f; sp += p;
        }
        #pragma unroll
        for (int k = 0; k < 14; ++k) {
            int vr = vr0 + k;
            int gy = reflect(ty0 + vr);
            float f = fcol[gy*WW], im = icol[gy*WW];
            float p = f*im;
            sf += f; sp += p;
            float2 st; st.x = sf; st.y = sp;
            *(float2*)(S + vr*PTW + 2*col) = st;
            sf -= rf[k%11]; sp -= rp[k%11];
            rf[(k+10)%11] = f; rp[(k+10)%11] = p;
        }
    }
    __syncthreads();

    // ---- Phase B: horizontal 11-sums -> {mp,cip}; b128; prefetch-4 pipelined ----
    // 42 rows x 2 col-segs = 84 threads; seg0 reads units 0..23 writes 0..18;
    // seg1 reads 19..41 writes 24..41.
    if (t < 84) {
        int seg = (t >= 42) ? 1 : 0;
        int vr  = t - seg*42;
        float* row = S + vr*PTW;
        int xbu = seg*19;
        int nout = seg ? 18 : 19;
        float4 ring[5];
        float TF = 0.f, TP = 0.f;
        #pragma unroll
        for (int j = 0; j < 5; ++j) {
            float4 v = *(float4*)(row + 4*(xbu + j));
            ring[j] = v; TF += v.x + v.z; TP += v.y + v.w;
        }
        float4 pre[4];
        #pragma unroll
        for (int j = 0; j < 4; ++j)
            pre[j] = *(float4*)(row + 4*(xbu + 5 + j));
        #pragma unroll
        for (int k = 0; k < 19; ++k) {
            if (k < nout) {
                float4 p = pre[k & 3];
                int nk = k + 4;
                if (nk < nout) pre[k & 3] = *(float4*)(row + 4*(xbu + 5 + nk));
                float4 q = ring[k % 5];
                float O0f = TF + p.x;
                float O1f = O0f + p.z - q.x;
                TF = O1f - q.z;
                float O0p = TP + p.y;
                float O1p = O0p + p.w - q.y;
                TP = O1p - q.w;
                ring[k % 5] = p;
                float4 o;
                o.x = O0f*inv121; o.y = O0p*inv121;
                o.z = O1f*inv121; o.w = O1p*inv121;
                *(float4*)(row + 4*(k + xbu + 5*seg)) = o;
            }
        }
    }
    __syncthreads();

    // ---- Phase B2: a,b elementwise; explicit next-job prefetch (LDS + miv) ----
    {
        const int NJ = VR*37;    // 1554 jobs
        int i = t;
        float* cell = S;
        float4 mc = {};
        float2 g0 = {}, g1 = {};
        if (i < NJ) {
            int y = i / 37, u = i - y*37;
            int su = u + ((u >= 19) ? 5 : 0);
            cell = S + y*PTW + 4*su;
            mc = *(float4*)cell;
            int gy = reflect(ty0 - 5 + y);
            const float2* mrow = mivb + gy*WW;
            int gx0 = tx0 - 5 + 2*u;
            g0 = mrow[reflect(gx0)];
            g1 = mrow[reflect(gx0+1)];
        }
        while (i < NJ) {
            int inext = i + 512;
            float* celln = cell;
            float4 mcn = {};
            float2 g0n = {}, g1n = {};
            if (inext < NJ) {
                int yn = inext / 37, un = inext - yn*37;
                int sun = un + ((un >= 19) ? 5 : 0);
                celln = S + yn*PTW + 4*sun;
                mcn = *(float4*)celln;
                int gyn = reflect(ty0 - 5 + yn);
                const float2* mrown = mivb + gyn*WW;
                int gx0n = tx0 - 5 + 2*un;
                g0n = mrown[reflect(gx0n)];
                g1n = mrown[reflect(gx0n+1)];
            }
            float a0 = (mc.y - g0.x*mc.x) * g0.y;
            float b0 = mc.x - a0*g0.x;
            float a1 = (mc.w - g1.x*mc.z) * g1.y;
            float b1 = mc.z - a1*g1.x;
            float4 o; o.x = a0; o.y = b0; o.z = a1; o.w = b1;
            *(float4*)cell = o;
            i = inext; cell = celln; mc = mcn; g0 = g0n; g1 = g1n;
        }
    }
    __syncthreads();

    // ---- Phase C: vertical 11-sums of {a,b}; b64 per col; prefetch-4 pipelined ----
    // 74 cols x 2 row-segs(16) = 148 threads.
    // seg0: reads rows 0..25, writes 0..15. seg1: reads 16..41, writes 26..41.
    if (t < 148) {
        int seg = (t >= 74) ? 1 : 0;
        int c   = t - seg*74;
        int sw  = 2*(c + ((c >= 38) ? 10 : 0));
        int y0  = seg*16;
        float2 ring[11];
        float sa = 0.f, sb = 0.f;
        #pragma unroll
        for (int j = 0; j < 10; ++j) {
            float2 v = *(float2*)(S + (y0+j)*PTW + sw);
            ring[j] = v; sa += v.x; sb += v.y;
        }
        float2 pre[4];
        #pragma unroll
        for (int j = 0; j < 4; ++j)
            pre[j] = *(float2*)(S + (y0+10+j)*PTW + sw);
        #pragma unroll
        for (int k = 0; k < 16; ++k) {
            float2 v = pre[k & 3];
            if (k + 4 < 16) pre[k & 3] = *(float2*)(S + (y0+14+k)*PTW + sw);
            sa += v.x; sb += v.y;
            int wrow = y0 + k + 10*seg;
            float2 o; o.x = sa; o.y = sb;
            *(float2*)(S + wrow*PTW + sw) = o;
            sa -= ring[k%11].x; sb -= ring[k%11].y;
            ring[(k+10)%11] = v;
        }
    }
    __syncthreads();

    // ---- Phase D: horizontal 11-sums of {sa,sb}; b128; prefetch-4 pipelined ----
    // 32 rows x 2 col-segs = 64 threads.
    if (t < 64) {
        int seg = t >> 5, row = t & 31;
        int prow = row + ((row >= 16) ? 10 : 0);
        float* rw = S + prow*PTW;
        int ub = seg*16;
        float4 ring[5];
        float TA = 0.f, TB = 0.f;
        #pragma unroll
        for (int j = 0; j < 5; ++j) {
            int u = ub + j; int su = u + ((u >= 19) ? 5 : 0);
            float4 v = *(float4*)(rw + 4*su);
            ring[j] = v; TA += v.x + v.z; TB += v.y + v.w;
        }
        float4 pre[4];
        #pragma unroll
        for (int j = 0; j < 4; ++j) {
            int u = ub + 5 + j; int su = u + ((u >= 19) ? 5 : 0);
            pre[j] = *(float4*)(rw + 4*su);
        }
        #pragma unroll
        for (int k = 0; k < 16; ++k) {
            float4 p = pre[k & 3];
            if (k + 4 < 16) {
                int u = ub + 9 + k; int su = u + ((u >= 19) ? 5 : 0);
                pre[k & 3] = *(float4*)(rw + 4*su);
            }
            float4 q = ring[k % 5];
            float A0 = TA + p.x;
            float A1 = A0 + p.z - q.x;
            TA = A1 - q.z;
            float B0 = TB + p.y;
            float B1 = B0 + p.w - q.y;
            TB = B1 - q.w;
            ring[k % 5] = p;
            float4 o; o.x = A0; o.y = B0; o.z = A1; o.w = B1;
            *(float4*)(rw + 4*(ub + k) + 40*seg) = o;
        }
    }
    __syncthreads();

    // ---- Phase D2: combine + coalesced float2 store (read-only LDS) ----
    float* ob = out + (size_t)bd*HW;
    for (int i = t; i < TH*32; i += 512) {
        int row = i >> 5, u = i & 31;
        int prow = row + ((row >= 16) ? 10 : 0);
        int ww = 4*u + ((u >= 16) ? 40 : 0);
        float4 s4 = *(float4*)(S + prow*PTW + ww);
        int gy = ty0 + row;
        int x0 = 2*u;
        float2 im2 = *(const float2*)(ib + gy*WW + tx0 + x0);
        float2 o;
        o.x = (s4.x*im2.x + s4.y)*inv121;
        o.y = (s4.z*im2.y + s4.w)*inv121;
        *(float2*)(ob + gy*WW + tx0 + x0) = o;
    }
}

extern "C" void kernel_launch(void* const* d_in, const int* in_sizes, int n_in,
                              void* d_out, int out_size, void* d_ws, size_t ws_size,
                              hipStream_t stream) {
    const float* feat = (const float*)d_in[0];
    const float* img  = (const float*)d_in[1];
    float* out  = (float*)d_out;
    float2* miv = (float2*)d_ws;             // NB*HW float2 = 16 MiB

    img_stats<<<NB*128, 256, 0, stream>>>(img, miv);
    guided_main<<<NB*ND*128, 512, 0, stream>>>(feat, img, miv, out);
}

// Round 23
// 145.218 us; speedup vs baseline: 1.7858x; 1.7858x over previous
//
#include <hip/hip_runtime.h>

#define HH 512
#define WW 512
#define HW (512*512)
#define NB 8
#define ND 16
#define TW 64            // tile width (output)
#define TH 64            // tile height (output)
#define VR 74            // v-sum rows = TH+10
#define PTW 172          // words/row: 84 cols x {F,P} + 4 pad; 172/4=43 odd ->
                         // row-lane b128 hits all 8 bank-quads bijectively

__device__ __forceinline__ int reflect(int v) {
    if (v < 0) v = -v;
    if (v >= HH) v = 2*HH - 2 - v;
    return v;
}

// ---------------- Prepass: {mean_I, 1/(var_I+eps)} interleaved float2 ----------------
__global__ __launch_bounds__(256) void img_stats(const float* __restrict__ img,
                                                 float2* __restrict__ miv) {
    const int VRs = 42, PTs = 86, THs = 32, TWs = 64;
    __shared__ __align__(16) float hBuf[2*VRs*PTs + 20];
    float* hF = hBuf;
    float* hP = hBuf + VRs*PTs + 20;

    int blk  = blockIdx.x;
    int tile = blk & 127;
    int b    = blk >> 7;
    int ty0  = (tile >> 3) * THs;
    int tx0  = (tile & 7)  * TWs;

    const float inv121 = 1.0f/121.0f;
    const float* ib = img + (size_t)b*HW;
    const int t = threadIdx.x;

    if (t < 252) {
        int seg = t / 84, col = t - seg*84;
        int gx = reflect(tx0 - 10 + col);
        const float* icol = ib + gx;
        int vr0 = seg*14;
        float rv[11], rq[11];
        float sv = 0.f, sq = 0.f;
        #pragma unroll
        for (int j = 0; j < 10; ++j) {
            int gy = reflect(ty0 - 10 + vr0 + j);
            float v = icol[gy*WW], q = v*v;
            rv[j] = v; rq[j] = q; sv += v; sq += q;
        }
        #pragma unroll
        for (int k = 0; k < 14; ++k) {
            int vr = vr0 + k;
            int gy = reflect(ty0 + vr);
            float v = icol[gy*WW], q = v*v;
            sv += v; sq += q;
            hF[vr*PTs + col] = sv;
            hP[vr*PTs + col] = sq;
            sv -= rv[k%11]; sq -= rq[k%11];
            rv[(k+10)%11] = v; rq[(k+10)%11] = q;
        }
    }
    __syncthreads();

    if (t < 168) {
        int arr = t & 1;
        int j2  = t >> 1;
        int seg = (j2 >= 42) ? 1 : 0;
        int vr  = j2 - seg*42;
        int xb = seg ? 38 : 0;
        int nout = seg ? 18 : 19;
        float* rA = (arr ? hP : hF) + vr*PTs;
        float2 ring[5];
        float T = 0.f;
        #pragma unroll
        for (int j = 0; j < 5; ++j) {
            float2 v = *(float2*)(rA + xb + 2*j);
            ring[j] = v; T += v.x + v.y;
        }
        #pragma unroll
        for (int k2 = 0; k2 < 19; ++k2) {
            if (k2 < nout) {
                int hc = xb + 2*k2;
                float2 p = *(float2*)(rA + hc + 10);
                float2 q = ring[k2 % 5];
                float O0 = T + p.x;
                float O1 = O0 + p.y - q.x;
                T = O1 - q.y;
                ring[k2 % 5] = p;
                float2 o; o.x = O0*inv121; o.y = O1*inv121;
                *(float2*)(rA + hc + 10*seg) = o;
            }
        }
    }
    __syncthreads();

    float2* mb = miv + (size_t)b*HW;
    for (int i = t; i < THs*TWs; i += 256) {
        int y = i >> 6, x = i & 63;
        int vr = y + 5, hc = x + 5;
        int slot = hc + ((hc >= 38) ? 10 : 0);
        float mI  = hF[vr*PTs + slot];
        float mII = hP[vr*PTs + slot];
        float var = mII - mI*mI;
        float2 o; o.x = mI; o.y = 1.0f / (var + 1e-8f);
        mb[(ty0 + y)*WW + tx0 + x] = o;
    }
}

// ---------------- Main fused kernel: one (b,d) channel, one 64x64 tile, 512 thr --------
// R16 structure; launch_bounds(512,6) matches the LDS-imposed 6 waves/EU so the
// compiler can use ~80 VGPRs; LDS prefetch deepened to 4 in B/C/D.
// Prefetch safety (depth 4): every prefetched unit/row is overwritten no earlier
// than 4 iterations after it is read (B seg1: read unit 28+k at iter k, written
// at k+4; C seg1: read row 46+k at k, written at k+4; D seg1: read su 30+k at k,
// written at k+4; all seg0 margins >= 9). Warm-up reads precede all in-loop writes.
__global__ __launch_bounds__(512, 6) void guided_main(const float* __restrict__ feat,
                                                      const float* __restrict__ img,
                                                      const float2* __restrict__ miv,
                                                      float* __restrict__ out) {
    __shared__ __align__(16) float S[VR*PTW];

    int blk  = blockIdx.x;
    int tile = blk & 63;         // 8 col-tiles x 8 row-tiles
    int bd   = blk >> 6;
    int b    = bd >> 4;
    int ty0  = (tile >> 3) * TH;
    int tx0  = (tile & 7)  * TW;

    const float inv121 = 1.0f/121.0f;
    const float* fb   = feat + (size_t)bd*HW;
    const float* ib   = img  + (size_t)b*HW;
    const float2* mivb = miv + (size_t)b*HW;
    const int t = threadIdx.x;

    // ---- Phase A: vertical raw 11-sums; one b64 {sf,sp} store (writes only) ----
    if (t < 504) {
        int seg = t / 84, col = t - seg*84;
        int gx = reflect(tx0 - 10 + col);
        const float* fcol = fb + gx;
        const float* icol = ib + gx;
        int vr0 = seg*13;
        float rf[11], rp[11];
        float sf = 0.f, sp = 0.f;
        #pragma unroll
        for (int j = 0; j < 10; ++j) {
            int gy = reflect(ty0 - 10 + vr0 + j);
            float f = fcol[gy*WW], im = icol[gy*WW];
            float p = f*im;
            rf[j] = f; rp[j] = p; sf += f; sp += p;
        }
        #pragma unroll
        for (int k = 0; k < 13; ++k) {
            int vr = vr0 + k;
            if (vr < VR) {
                int gy = reflect(ty0 + vr);
                float f = fcol[gy*WW], im = icol[gy*WW];
                float p = f*im;
                sf += f; sp += p;
                float2 st; st.x = sf; st.y = sp;
                *(float2*)(S + vr*PTW + 2*col) = st;
                sf -= rf[k%11]; sp -= rp[k%11];
                rf[(k+10)%11] = f; rp[(k+10)%11] = p;
            }
        }
    }
    __syncthreads();

    // ---- Phase B: horizontal 11-sums -> {mp,cip}; b128; prefetch-4 pipelined ----
    if (t < 148) {
        int seg = (t >= 74) ? 1 : 0;
        int vr  = t - seg*74;
        float* row = S + vr*PTW;
        int xbu = seg*19;
        int nout = seg ? 18 : 19;
        float4 ring[5];
        float TF = 0.f, TP = 0.f;
        #pragma unroll
        for (int j = 0; j < 5; ++j) {
            float4 v = *(float4*)(row + 4*(xbu + j));
            ring[j] = v; TF += v.x + v.z; TP += v.y + v.w;
        }
        float4 pre[4];
        #pragma unroll
        for (int j = 0; j < 4; ++j)
            pre[j] = *(float4*)(row + 4*(xbu + 5 + j));
        #pragma unroll
        for (int k = 0; k < 19; ++k) {
            if (k < nout) {
                float4 p = pre[k & 3];
                int nk = k + 4;
                if (nk < nout) pre[k & 3] = *(float4*)(row + 4*(xbu + 5 + nk));
                float4 q = ring[k % 5];
                float O0f = TF + p.x;
                float O1f = O0f + p.z - q.x;
                TF = O1f - q.z;
                float O0p = TP + p.y;
                float O1p = O0p + p.w - q.y;
                TP = O1p - q.w;
                ring[k % 5] = p;
                float4 o;
                o.x = O0f*inv121; o.y = O0p*inv121;
                o.z = O1f*inv121; o.w = O1p*inv121;
                *(float4*)(row + 4*(k + xbu + 5*seg)) = o;
            }
        }
    }
    __syncthreads();

    // ---- Phase B2: a,b elementwise; explicit next-job prefetch (LDS + miv) ----
    {
        const int NJ = VR*37;
        int i = t;
        float* cell = S;
        float4 mc = {};
        float2 g0 = {}, g1 = {};
        if (i < NJ) {
            int y = i / 37, u = i - y*37;
            int su = u + ((u >= 19) ? 5 : 0);
            cell = S + y*PTW + 4*su;
            mc = *(float4*)cell;
            int gy = reflect(ty0 - 5 + y);
            const float2* mrow = mivb + gy*WW;
            int gx0 = tx0 - 5 + 2*u;
            g0 = mrow[reflect(gx0)];
            g1 = mrow[reflect(gx0+1)];
        }
        while (i < NJ) {
            int inext = i + 512;
            float* celln = cell;
            float4 mcn = {};
            float2 g0n = {}, g1n = {};
            if (inext < NJ) {
                int yn = inext / 37, un = inext - yn*37;
                int sun = un + ((un >= 19) ? 5 : 0);
                celln = S + yn*PTW + 4*sun;
                mcn = *(float4*)celln;
                int gyn = reflect(ty0 - 5 + yn);
                const float2* mrown = mivb + gyn*WW;
                int gx0n = tx0 - 5 + 2*un;
                g0n = mrown[reflect(gx0n)];
                g1n = mrown[reflect(gx0n+1)];
            }
            float a0 = (mc.y - g0.x*mc.x) * g0.y;
            float b0 = mc.x - a0*g0.x;
            float a1 = (mc.w - g1.x*mc.z) * g1.y;
            float b1 = mc.z - a1*g1.x;
            float4 o; o.x = a0; o.y = b0; o.z = a1; o.w = b1;
            *(float4*)cell = o;
            i = inext; cell = celln; mc = mcn; g0 = g0n; g1 = g1n;
        }
    }
    __syncthreads();

    // ---- Phase C: vertical 11-sums of {a,b}; b64 per col; prefetch-4 pipelined ----
    if (t < 148) {
        int seg = (t >= 74) ? 1 : 0;
        int c   = t - seg*74;
        int sw  = 2*(c + ((c >= 38) ? 10 : 0));
        int y0  = seg*32;
        float2 ring[11];
        float sa = 0.f, sb = 0.f;
        #pragma unroll
        for (int j = 0; j < 10; ++j) {
            float2 v = *(float2*)(S + (y0+j)*PTW + sw);
            ring[j] = v; sa += v.x; sb += v.y;
        }
        float2 pre[4];
        #pragma unroll
        for (int j = 0; j < 4; ++j)
            pre[j] = *(float2*)(S + (y0+10+j)*PTW + sw);
        #pragma unroll
        for (int k = 0; k < 32; ++k) {
            float2 v = pre[k & 3];
            if (k + 4 < 32) pre[k & 3] = *(float2*)(S + (y0+14+k)*PTW + sw);
            sa += v.x; sb += v.y;
            int wrow = y0 + k + 10*seg;
            float2 o; o.x = sa; o.y = sb;
            *(float2*)(S + wrow*PTW + sw) = o;
            sa -= ring[k%11].x; sb -= ring[k%11].y;
            ring[(k+10)%11] = v;
        }
    }
    __syncthreads();

    // ---- Phase D: horizontal 11-sums of {sa,sb}; b128; prefetch-4 pipelined ----
    if (t < 128) {
        int seg = t >> 6, row = t & 63;
        int prow = row + ((row >= 32) ? 10 : 0);
        float* rw = S + prow*PTW;
        int ub = seg*16;
        float4 ring[5];
        float TA = 0.f, TB = 0.f;
        #pragma unroll
        for (int j = 0; j < 5; ++j) {
            int u = ub + j; int su = u + ((u >= 19) ? 5 : 0);
            float4 v = *(float4*)(rw + 4*su);
            ring[j] = v; TA += v.x + v.z; TB += v.y + v.w;
        }
        float4 pre[4];
        #pragma unroll
        for (int j = 0; j < 4; ++j) {
            int u = ub + 5 + j; int su = u + ((u >= 19) ? 5 : 0);
            pre[j] = *(float4*)(rw + 4*su);
        }
        #pragma unroll
        for (int k = 0; k < 16; ++k) {
            float4 p = pre[k & 3];
            if (k + 4 < 16) {
                int u = ub + 9 + k; int su = u + ((u >= 19) ? 5 : 0);
                pre[k & 3] = *(float4*)(rw + 4*su);
            }
            float4 q = ring[k % 5];
            float A0 = TA + p.x;
            float A1 = A0 + p.z - q.x;
            TA = A1 - q.z;
            float B0 = TB + p.y;
            float B1 = B0 + p.w - q.y;
            TB = B1 - q.w;
            ring[k % 5] = p;
            float4 o; o.x = A0; o.y = B0; o.z = A1; o.w = B1;
            *(float4*)(rw + 4*(ub + k) + 40*seg) = o;
        }
    }
    __syncthreads();

    // ---- Phase D2: combine + coalesced float2 store (read-only LDS) ----
    float* ob = out + (size_t)bd*HW;
    for (int i = t; i < TH*32; i += 512) {
        int row = i >> 5, u = i & 31;
        int prow = row + ((row >= 32) ? 10 : 0);
        int ww = 4*u + ((u >= 16) ? 40 : 0);
        float4 s4 = *(float4*)(S + prow*PTW + ww);
        int gy = ty0 + row;
        int x0 = 2*u;
        float2 im2 = *(const float2*)(ib + gy*WW + tx0 + x0);
        float2 o;
        o.x = (s4.x*im2.x + s4.y)*inv121;
        o.y = (s4.z*im2.y + s4.w)*inv121;
        *(float2*)(ob + gy*WW + tx0 + x0) = o;
    }
}

extern "C" void kernel_launch(void* const* d_in, const int* in_sizes, int n_in,
                              void* d_out, int out_size, void* d_ws, size_t ws_size,
                              hipStream_t stream) {
    const float* feat = (const float*)d_in[0];
    const float* img  = (const float*)d_in[1];
    float* out  = (float*)d_out;
    float2* miv = (float2*)d_ws;             // NB*HW float2 = 16 MiB

    img_stats<<<NB*128, 256, 0, stream>>>(img, miv);
    guided_main<<<NB*ND*64, 512, 0, stream>>>(feat, img, miv, out);
}